// Round 3
// baseline (283.660 us; speedup 1.0000x reference)
//
#include <hip/hip_runtime.h>
#include <hip/hip_bf16.h>

typedef __bf16 bf16x8 __attribute__((ext_vector_type(8)));
typedef float  f32x16 __attribute__((ext_vector_type(16)));

#define ALPHA_W 0.4f
#define NTOT 65536.0f

// output layout (float elements): [out 4*256*128*128][cov 8*32*32][eigen 32*32*32]
#define OUT_MAIN 16777216
#define OUT_COV  (OUT_MAIN)
#define OUT_EIG  (OUT_MAIN + 8192)

// ws layout (float offsets)
#define WS_PSXY 0          // 256 blocks * 1024
#define WS_PSX  262144     // 256 blocks * 32
#define WS_M    270336     // 32*1024  (M = alpha*UDU + 0.6*I per (b,g))
#define WS_T    303104     // 32*32

struct Ptrs {
    const float* ctw[5]; const float* ctb[5];
    const float* muw[3]; const float* mub[3];
};

// ---------- Kernel A: per-group raw gram + channel sums, per-block partials ----------
// grid 256: g = bid>>5, slice = bid&31 (2048-wide n-slice). MFMA gram: A-frag == B-frag.
__global__ __launch_bounds__(256) void gram_kernel(const float* __restrict__ cA,
                                                   float* __restrict__ pSXY,
                                                   float* __restrict__ pSX) {
    int bid = blockIdx.x;
    int g = bid >> 5, slice = bid & 31;
    int tid = threadIdx.x;
    int w = tid >> 6, l = tid & 63;
    int col = l & 31, kq = l >> 5;
    int nbase = slice * 2048 + w * 512;       // stays inside one b (b = nbase>>14)
    int b = nbase >> 14;
    int hw0 = nbase & 16383;
    const float* base = cA + (((size_t)(b * 256 + g * 32 + col)) << 14) + hw0 + kq * 8;

    f32x16 acc;
    #pragma unroll
    for (int r = 0; r < 16; r++) acc[r] = 0.f;
    float s0 = 0.f, s1 = 0.f;
    for (int it = 0; it < 32; ++it) {
        float4 f0 = *(const float4*)(base + it * 16);
        float4 f1 = *(const float4*)(base + it * 16 + 4);
        s0 += (f0.x + f0.y) + (f0.z + f0.w);
        s1 += (f1.x + f1.y) + (f1.z + f1.w);
        bf16x8 v;
        v[0] = (__bf16)f0.x; v[1] = (__bf16)f0.y; v[2] = (__bf16)f0.z; v[3] = (__bf16)f0.w;
        v[4] = (__bf16)f1.x; v[5] = (__bf16)f1.y; v[6] = (__bf16)f1.z; v[7] = (__bf16)f1.w;
        acc = __builtin_amdgcn_mfma_f32_32x32x16_bf16(v, v, acc, 0, 0, 0);
    }
    __shared__ float red[4][1024];
    __shared__ float sxr[4][64];
    sxr[w][l] = s0 + s1;
    #pragma unroll
    for (int r = 0; r < 16; r++) {
        int i = (r & 3) + 8 * (r >> 2) + 4 * kq;   // 32x32 C/D layout (symmetric matrix)
        red[w][i * 32 + col] = acc[r];
    }
    __syncthreads();
    for (int e = tid; e < 1024; e += 256) {
        pSXY[(size_t)bid * 1024 + e] = red[0][e] + red[1][e] + red[2][e] + red[3][e];
    }
    if (tid < 32) {
        float v = 0.f;
        #pragma unroll
        for (int ww = 0; ww < 4; ww++) v += sxr[ww][tid] + sxr[ww][tid + 32];
        pSX[bid * 32 + tid] = v;
    }
}

// 4-way unrolled 256-dot: w from global (L2), x from LDS (broadcast reads)
__device__ inline float dot256(const float* __restrict__ w, const float* __restrict__ x) {
    float a0 = 0.f, a1 = 0.f, a2 = 0.f, a3 = 0.f;
    for (int i = 0; i < 256; i += 16) {
        float4 w0 = *(const float4*)(w + i);
        float4 w1 = *(const float4*)(w + i + 4);
        float4 w2 = *(const float4*)(w + i + 8);
        float4 w3 = *(const float4*)(w + i + 12);
        a0 = fmaf(w0.x, x[i + 0], a0);  a0 = fmaf(w0.y, x[i + 1], a0);
        a0 = fmaf(w0.z, x[i + 2], a0);  a0 = fmaf(w0.w, x[i + 3], a0);
        a1 = fmaf(w1.x, x[i + 4], a1);  a1 = fmaf(w1.y, x[i + 5], a1);
        a1 = fmaf(w1.z, x[i + 6], a1);  a1 = fmaf(w1.w, x[i + 7], a1);
        a2 = fmaf(w2.x, x[i + 8], a2);  a2 = fmaf(w2.y, x[i + 9], a2);
        a2 = fmaf(w2.z, x[i + 10], a2); a2 = fmaf(w2.w, x[i + 11], a2);
        a3 = fmaf(w3.x, x[i + 12], a3); a3 = fmaf(w3.y, x[i + 13], a3);
        a3 = fmaf(w3.z, x[i + 14], a3); a3 = fmaf(w3.w, x[i + 15], a3);
    }
    return (a0 + a1) + (a2 + a3);
}

__device__ inline float lrelu(float x) { return x >= 0.f ? x : 0.01f * x; }

// ---------- Kernel B: whole MLP chain + finalize, one launch ----------
// blocks 0..31: (b,g) -> full ct chain, mu chain (redundant per b), D/U/eigen, UDU -> M, T
// blocks 32..39: g -> reduce gram partials -> cov
__global__ __launch_bounds__(256) void mlp_finalize(const float* __restrict__ sB,
                                                    Ptrs p,
                                                    const float* __restrict__ pSXY,
                                                    const float* __restrict__ pSX,
                                                    float* __restrict__ M,
                                                    float* __restrict__ T,
                                                    float* __restrict__ out) {
    int bid = blockIdx.x;
    int t = threadIdx.x;
    if (bid < 32) {
        int b = bid >> 3, g = bid & 7;
        __shared__ float ha[256], hb[256];
        __shared__ float sct[32 * 33], uu[32 * 33], ud[32 * 33];
        __shared__ float dinv[32], sxg[32];
        // stage x0 (32 style dims for this group) + reduce channel sums for this group
        if (t < 32) {
            ha[t] = sB[b * 256 + g * 32 + t];
            float s = 0.f;
            for (int sl = 0; sl < 32; sl++) s += pSX[(g * 32 + sl) * 32 + t];
            sxg[t] = s * (1.0f / NTOT);   // per-channel mean
        }
        __syncthreads();
        // ct L0: 32 -> 256
        {
            const float* wr = p.ctw[0] + t * 32;
            float a0 = 0.f, a1 = 0.f;
            #pragma unroll
            for (int i = 0; i < 32; i += 8) {
                float4 w0 = *(const float4*)(wr + i);
                float4 w1 = *(const float4*)(wr + i + 4);
                a0 = fmaf(w0.x, ha[i + 0], a0); a0 = fmaf(w0.y, ha[i + 1], a0);
                a0 = fmaf(w0.z, ha[i + 2], a0); a0 = fmaf(w0.w, ha[i + 3], a0);
                a1 = fmaf(w1.x, ha[i + 4], a1); a1 = fmaf(w1.y, ha[i + 5], a1);
                a1 = fmaf(w1.z, ha[i + 6], a1); a1 = fmaf(w1.w, ha[i + 7], a1);
            }
            hb[t] = lrelu(a0 + a1 + p.ctb[0][t]);
        }
        __syncthreads();
        // ct L1..L3: 256 -> 256, ping-pong hb->ha->hb->ha
        ha[t] = lrelu(dot256(p.ctw[1] + t * 256, hb) + p.ctb[1][t]);  __syncthreads();
        hb[t] = lrelu(dot256(p.ctw[2] + t * 256, ha) + p.ctb[2][t]);  __syncthreads();
        ha[t] = lrelu(dot256(p.ctw[3] + t * 256, hb) + p.ctb[3][t]);  __syncthreads();
        // ct L4: 256 -> 1024 (s_CT), 4 outputs per thread, no act
        #pragma unroll
        for (int q = 0; q < 4; q++) {
            int o = t + 256 * q;
            float v = dot256(p.ctw[4] + (size_t)o * 256, ha) + p.ctb[4][o];
            sct[(o >> 5) * 33 + (o & 31)] = v;
        }
        __syncthreads();
        // mu chain (reuse ha/hb): full 256-dim style row of batch b
        ha[t] = sB[b * 256 + t];                                      __syncthreads();
        hb[t] = lrelu(dot256(p.muw[0] + t * 256, ha) + p.mub[0][t]);  __syncthreads();
        ha[t] = lrelu(dot256(p.muw[1] + t * 256, hb) + p.mub[1][t]);  __syncthreads();
        hb[t] = dot256(p.muw[2] + t * 256, ha) + p.mub[2][t];         // s_mu, no act
        // column norms -> dinv
        if (t < 32) {
            float s = 0.f;
            for (int i = 0; i < 32; i++) { float v = sct[i * 33 + t]; s = fmaf(v, v, s); }
            dinv[t] = 1.0f / sqrtf(s);
        }
        __syncthreads();
        // U + eigen_s output (group-major g*B+b)
        float* eig = out + OUT_EIG + (size_t)(g * 4 + b) * 1024;
        for (int e = t; e < 1024; e += 256) {
            int i = e >> 5, jj = e & 31;
            float u = sct[i * 33 + jj] * dinv[jj];
            uu[i * 33 + jj] = u;
            eig[e] = u;
        }
        __syncthreads();
        // UDU -> M = alpha*UDU + 0.6*I
        float* Mo = M + (size_t)bid * 1024;
        for (int e = t; e < 1024; e += 256) {
            int i = e >> 5, k = e & 31;
            float s = 0.f;
            for (int jv = 0; jv < 32; jv++) s = fmaf(sct[i * 33 + jv], uu[k * 33 + jv], s);
            ud[i * 33 + k] = s;
            Mo[e] = ALPHA_W * s + (i == k ? (1.0f - ALPHA_W) : 0.0f);
        }
        __syncthreads();
        // T = alpha * (s_mu - UDU @ mean)
        if (t < 32) {
            float s = 0.f;
            for (int k = 0; k < 32; k++) s = fmaf(ud[t * 33 + k], sxg[k], s);
            T[bid * 32 + t] = ALPHA_W * (hb[g * 32 + t] - s);
        }
    } else {
        int g = bid - 32;
        __shared__ float sxg[32];
        if (t < 32) {
            float s = 0.f;
            for (int sl = 0; sl < 32; sl++) s += pSX[(g * 32 + sl) * 32 + t];
            sxg[t] = s * (1.0f / NTOT);
        }
        __syncthreads();
        float* cov = out + OUT_COV + (size_t)g * 1024;
        for (int e = t; e < 1024; e += 256) {
            float s = 0.f;
            for (int sl = 0; sl < 32; sl++) s += pSXY[(size_t)(g * 32 + sl) * 1024 + e];
            int i = e >> 5, jj = e & 31;
            float v = (s - NTOT * sxg[i] * sxg[jj]) * (1.0f / (NTOT - 1.0f));
            if (i == jj) v += 1e-5f;
            cov[e] = v;
        }
    }
}

// ---------- Kernel C: out[b, g*32+i, n] = sum_k M[i,k]*cA[b, g*32+k, n] + t[i] ----------
// grid 1024: bg = bid>>5, chunk = bid&31 (512-wide hw chunk); 8 tiles of 64 cols,
// double-buffered LDS, ONE sync per tile, float4 LDS stores (conflict-free b128).
__global__ __launch_bounds__(256) void color_kernel(const float* __restrict__ cA,
                                                    const float* __restrict__ M,
                                                    const float* __restrict__ T,
                                                    float* __restrict__ out) {
    int bid = blockIdx.x;
    int bg = bid >> 5, chunk = bid & 31;
    int b = bg >> 3, g = bg & 7;
    int tid = threadIdx.x;
    int n = tid & 63, ih = tid >> 6;
    __shared__ float Ml[1024];
    __shared__ float tl[32];
    __shared__ float xs[2][2048];
    for (int e = tid; e < 1024; e += 256) Ml[e] = M[(size_t)bg * 1024 + e];
    if (tid < 32) tl[tid] = T[bg * 32 + tid];
    size_t cbase = (((size_t)(b * 256 + g * 32)) << 14) + chunk * 512;
    int srow = tid >> 3, scol = (tid & 7) * 8;
    size_t obase = (((size_t)(b * 256 + g * 32 + ih * 8)) << 14) + chunk * 512 + n;
    for (int tile = 0; tile < 8; ++tile) {
        const float* src = cA + cbase + (size_t)srow * 16384 + tile * 64 + scol;
        float4 u0 = *(const float4*)src;
        float4 u1 = *(const float4*)(src + 4);
        float* xd = &xs[tile & 1][srow * 64 + scol];
        *(float4*)xd = u0;
        *(float4*)(xd + 4) = u1;
        __syncthreads();
        const float* xb = xs[tile & 1];
        float acc[8];
        #pragma unroll
        for (int i = 0; i < 8; i++) acc[i] = tl[ih * 8 + i];
        for (int k = 0; k < 32; k++) {
            float xv = xb[k * 64 + n];
            #pragma unroll
            for (int i = 0; i < 8; i++) acc[i] = fmaf(Ml[(ih * 8 + i) * 32 + k], xv, acc[i]);
        }
        float* dst = out + obase + tile * 64;
        #pragma unroll
        for (int i = 0; i < 8; i++) dst[(size_t)i << 14] = acc[i];
    }
}

extern "C" void kernel_launch(void* const* d_in, const int* in_sizes, int n_in,
                              void* d_out, int out_size, void* d_ws, size_t ws_size,
                              hipStream_t stream) {
    (void)in_sizes; (void)n_in; (void)out_size; (void)ws_size;
    const float* cA = (const float*)d_in[0];
    const float* sB = (const float*)d_in[1];
    Ptrs p;
    p.ctw[0] = (const float*)d_in[3];  p.ctb[0] = (const float*)d_in[4];
    p.ctw[1] = (const float*)d_in[5];  p.ctb[1] = (const float*)d_in[6];
    p.ctw[2] = (const float*)d_in[7];  p.ctb[2] = (const float*)d_in[8];
    p.ctw[3] = (const float*)d_in[9];  p.ctb[3] = (const float*)d_in[10];
    p.ctw[4] = (const float*)d_in[11]; p.ctb[4] = (const float*)d_in[12];
    p.muw[0] = (const float*)d_in[13]; p.mub[0] = (const float*)d_in[14];
    p.muw[1] = (const float*)d_in[15]; p.mub[1] = (const float*)d_in[16];
    p.muw[2] = (const float*)d_in[17]; p.mub[2] = (const float*)d_in[18];
    float* W = (float*)d_ws;
    float* out = (float*)d_out;

    gram_kernel<<<256, 256, 0, stream>>>(cA, W + WS_PSXY, W + WS_PSX);
    mlp_finalize<<<40, 256, 0, stream>>>(sB, p, W + WS_PSXY, W + WS_PSX,
                                         W + WS_M, W + WS_T, out);
    color_kernel<<<1024, 256, 0, stream>>>(cA, W + WS_M, W + WS_T, out);
}